// Round 8
// baseline (664.034 us; speedup 1.0000x reference)
//
#include <hip/hip_runtime.h>
#include <math.h>

// dims
#define B_   64
#define P_   8
#define N1_  1152
#define N2_  128
#define D_   16

#define NSPLIT 16                      // i-splits for P1/P4 partials
#define CHUNK  (N1_ / NSPLIT)          // 72 i per chunk
#define NIB    (CHUNK / 4)             // 18 i-blocks of 4

#define GRID_BLKS 512                  // == P1/P4 vblocks; 2 blocks/CU guaranteed resident

typedef __attribute__((ext_vector_type(8)))  short bf16x8;
typedef __attribute__((ext_vector_type(4)))  float f32x4;
typedef __attribute__((ext_vector_type(16))) float f32x16;

// split 8 fp32 into hi/lo bf16 fragments (hi = truncate, lo = bf16(w - hi))
__device__ inline void split_frag(float4 a0, float4 a1, bf16x8& hi, bf16x8& lo)
{
    float w[8] = {a0.x, a0.y, a0.z, a0.w, a1.x, a1.y, a1.z, a1.w};
#pragma unroll
    for (int j = 0; j < 8; ++j) {
        unsigned ub = __float_as_uint(w[j]);
        hi[j] = (short)(ub >> 16);
        float hif = __uint_as_float(ub & 0xffff0000u);
        float r = w[j] - hif;
        lo[j] = (short)(__float_as_uint(r) >> 16);
    }
}

__device__ inline void split_arr(const float* w, bf16x8& hi, bf16x8& lo)
{
#pragma unroll
    for (int j = 0; j < 8; ++j) {
        unsigned ub = __float_as_uint(w[j]);
        hi[j] = (short)(ub >> 16);
        float hif = __uint_as_float(ub & 0xffff0000u);
        float r = w[j] - hif;
        lo[j] = (short)(__float_as_uint(r) >> 16);
    }
}

// pack 4 fp32 into hi/lo bf16 uint2 (same split formula — bit-identical frags)
__device__ inline void split4_pack(float4 s, uint2& hp, uint2& lp)
{
    float w[4] = {s.x, s.y, s.z, s.w};
    unsigned hs[4], ls[4];
#pragma unroll
    for (int j = 0; j < 4; ++j) {
        unsigned ub = __float_as_uint(w[j]);
        hs[j] = ub >> 16;
        float hif = __uint_as_float(ub & 0xffff0000u);
        float r = w[j] - hif;
        ls[j] = __float_as_uint(r) >> 16;
    }
    hp.x = hs[0] | (hs[1] << 16); hp.y = hs[2] | (hs[3] << 16);
    lp.x = ls[0] | (ls[1] << 16); lp.y = ls[2] | (ls[3] << 16);
}

// round fp32 -> bf16 bits (RNE), and the dequantized fp32 value
__device__ inline unsigned short bf16_rne(float x, float& deq)
{
    unsigned ub = __float_as_uint(x);
    unsigned r  = ub + 0x7fffu + ((ub >> 16) & 1u);
    unsigned short us = (unsigned short)(r >> 16);
    deq = __uint_as_float(((unsigned)us) << 16);
    return us;
}

// Hand-rolled grid barrier (one counter per sync point; counters pre-zeroed
// by the init kernel). Same fence/acquire pattern as ROCm's grid.sync():
// device-scope atomics + agent fences handle cross-XCD L2 writeback/inv.
__device__ inline void gbar(unsigned* __restrict__ bar, int k)
{
    __threadfence();                          // release this thread's writes (agent)
    __syncthreads();                          // whole block's writes ordered before arrival
    if (threadIdx.x == 0) {
        __hip_atomic_fetch_add(&bar[k], 1u, __ATOMIC_ACQ_REL, __HIP_MEMORY_SCOPE_AGENT);
        unsigned spins = 0;
        while (__hip_atomic_load(&bar[k], __ATOMIC_ACQUIRE, __HIP_MEMORY_SCOPE_AGENT)
               < (unsigned)GRID_BLKS) {
            __builtin_amdgcn_s_sleep(2);
            if (++spins > 400000000u) break;  // safety valve: fail loud, not hung
        }
    }
    __syncthreads();
}

// squash phase body: reduce NSPLIT partials (float4), scale, squash over d=16.
__device__ inline void squash_body(const float* __restrict__ spart,
                                   float* __restrict__ vout,
                                   unsigned short* __restrict__ v0h,
                                   unsigned short* __restrict__ v0l,
                                   float scale, int idx)
{
    float4 s = make_float4(0.f, 0.f, 0.f, 0.f);
    for (int sp = 0; sp < NSPLIT; ++sp) {
        float4 t = *(const float4*)(spart + (size_t)sp * (B_ * N2_ * D_) + (size_t)idx * 4);
        s.x += t.x; s.y += t.y; s.z += t.z; s.w += t.w;
    }
    s.x *= scale; s.y *= scale; s.z *= scale; s.w *= scale;
    float sq = s.x * s.x + s.y * s.y + s.z * s.z + s.w * s.w;
    sq += __shfl_xor(sq, 1);
    sq += __shfl_xor(sq, 2);
    float norm = sqrtf(sq + 1.1920929e-7f);
    float f = (sq / (1.f + sq)) / norm;
    float4 o = make_float4(s.x * f, s.y * f, s.z * f, s.w * f);
    *(float4*)(vout + (size_t)idx * 4) = o;
    if (v0h) {
        uint2 hp, lp;
        split4_pack(o, hp, lp);
        *(uint2*)(v0h + (size_t)idx * 4) = hp;
        *(uint2*)(v0l + (size_t)idx * 4) = lp;
    }
}

// ---------------------------------------------------------------------------
// INIT: zero barrier counters + softmax denominators (ws is re-poisoned
// between harness iterations, so this runs every launch). 288 x 256 = 73728.
// ---------------------------------------------------------------------------
__global__ __launch_bounds__(256) void kinit(float* __restrict__ denom,
                                             unsigned* __restrict__ bar)
{
    int z = blockIdx.x * 256 + threadIdx.x;
    denom[z] = 0.f;
    if (z < 8) bar[z] = 0u;
}

// ---------------------------------------------------------------------------
// MEGA: all 5 phases, one plain dispatch, hand-rolled grid barriers.
//  P1: s0 partials (512 vblocks == 512 blocks; R5 k1 body, direct-x split)
//  P2: squash->v0 (+bf16 planes)                        [blocks 0..127]
//  P3: e_t=bf16(exp(<v0,pred>)) + denom atomics (1152 vblocks, stride 512)
//  P4: s1 partials (512 vblocks; R5 k3c body)
//  P5: squash->out                                      [blocks 0..127]
// ---------------------------------------------------------------------------
__global__ __launch_bounds__(256, 2) void mega(const float* __restrict__ x,
                                               const float* __restrict__ W,
                                               float* __restrict__ out,
                                               float* __restrict__ s_part,
                                               float* __restrict__ v0,
                                               float* __restrict__ denom,
                                               unsigned short* __restrict__ v0h,
                                               unsigned short* __restrict__ v0l,
                                               unsigned short* __restrict__ e_t,
                                               unsigned* __restrict__ bar)
{
    const int blk  = blockIdx.x;
    const int tid  = threadIdx.x;
    const int lane = tid & 63;
    const int wv   = tid >> 6;

    __shared__ float dred[4][4][64];

    // ---------------- P1: s0 partials ----------------
    {
        const int col   = lane & 15;
        const int quad  = lane >> 4;
        const int n     = (blk & 31) * 4 + wv;
        const int isp   = blk >> 5;
        const int ibase = isp * CHUNK;

        f32x4 acc[4];
#pragma unroll
        for (int bt = 0; bt < 4; ++bt) acc[bt] = (f32x4){0.f, 0.f, 0.f, 0.f};

        for (int ib = 0; ib < NIB; ++ib) {
            const int iq = ibase + ib * 4 + quad;
            const float* wp = W + ((size_t)iq * N2_ + n) * (D_ * P_) + col * P_;
            float4 wa = *(const float4*)wp;
            float4 wb = *(const float4*)(wp + 4);
            bf16x8 ahi, alo;
            split_frag(wa, wb, ahi, alo);
#pragma unroll
            for (int bt = 0; bt < 4; ++bt) {
                const int b = bt * 16 + col;
                const float* xp = x + ((size_t)b * N1_ + iq) * P_;
                float4 xa = *(const float4*)xp;
                float4 xb = *(const float4*)(xp + 4);
                bf16x8 bhi, blo;
                split_frag(xa, xb, bhi, blo);
                acc[bt] = __builtin_amdgcn_mfma_f32_16x16x32_bf16(ahi, bhi, acc[bt], 0, 0, 0);
                acc[bt] = __builtin_amdgcn_mfma_f32_16x16x32_bf16(ahi, blo, acc[bt], 0, 0, 0);
                acc[bt] = __builtin_amdgcn_mfma_f32_16x16x32_bf16(alo, bhi, acc[bt], 0, 0, 0);
            }
        }
#pragma unroll
        for (int bt = 0; bt < 4; ++bt) {
            const int b = bt * 16 + col;
            float4 v = make_float4(acc[bt][0], acc[bt][1], acc[bt][2], acc[bt][3]);
            *(float4*)(s_part + (size_t)isp * (B_ * N2_ * D_) + (size_t)b * (N2_ * D_)
                       + n * D_ + quad * 4) = v;
        }
    }
    gbar(bar, 0);

    // ---------------- P2: squash -> v0 (+planes) ----------------
    if (blk < 128)
        squash_body(s_part, v0, v0h, v0l, 1.f / 128.f, blk * 256 + tid);
    gbar(bar, 1);

    // ---------------- P3: e_t + denom (1152 vblocks, stride 512) ----------
    for (int vb = blk; vb < 1152; vb += GRID_BLKS) {
        const int m    = lane & 31;
        const int kh   = lane >> 5;         // d-half in MFMA / p-half in epilogue
        const int isub = m >> 3;
        const int p    = m & 7;
        const int i0   = (vb >> 2) * 4;
        const int nbase = (vb & 3) * 32 + wv * 8;

        float4 xq0[4], xq1[4];
#pragma unroll
        for (int is = 0; is < 4; ++is) {
            xq0[is] = *(const float4*)(x + ((size_t)m * N1_ + i0 + is) * P_ + kh * 4);
            xq1[is] = *(const float4*)(x + ((size_t)(32 + m) * N1_ + i0 + is) * P_ + kh * 4);
        }

        float dacc[4] = {0.f, 0.f, 0.f, 0.f};

#pragma unroll 1
        for (int nt = 0; nt < 8; ++nt) {
            const int n = nbase + nt;

            bf16x8 vhi[2], vlo[2];
#pragma unroll
            for (int bt = 0; bt < 2; ++bt) {
                const size_t vo = (size_t)(bt * 32 + m) * (N2_ * D_) + n * D_ + kh * 8;
                vhi[bt] = *(const bf16x8*)(v0h + vo);
                vlo[bt] = *(const bf16x8*)(v0l + vo);
            }

            const float* wp = W + ((size_t)(i0 + isub) * N2_ + n) * (D_ * P_) + kh * 64 + p;
            float a[8];
#pragma unroll
            for (int j = 0; j < 8; ++j) a[j] = wp[8 * j];
            bf16x8 ahi, alo;
            split_arr(a, ahi, alo);

            f32x16 acc0, acc1;
#pragma unroll
            for (int r = 0; r < 16; ++r) { acc0[r] = 0.f; acc1[r] = 0.f; }
            acc0 = __builtin_amdgcn_mfma_f32_32x32x16_bf16(ahi, vhi[0], acc0, 0, 0, 0);
            acc0 = __builtin_amdgcn_mfma_f32_32x32x16_bf16(ahi, vlo[0], acc0, 0, 0, 0);
            acc0 = __builtin_amdgcn_mfma_f32_32x32x16_bf16(alo, vhi[0], acc0, 0, 0, 0);
            acc1 = __builtin_amdgcn_mfma_f32_32x32x16_bf16(ahi, vhi[1], acc1, 0, 0, 0);
            acc1 = __builtin_amdgcn_mfma_f32_32x32x16_bf16(ahi, vlo[1], acc1, 0, 0, 0);
            acc1 = __builtin_amdgcn_mfma_f32_32x32x16_bf16(alo, vhi[1], acc1, 0, 0, 0);

#pragma unroll
            for (int is = 0; is < 4; ++is) {
                float r0 = acc0[4 * is] * xq0[is].x + acc0[4 * is + 1] * xq0[is].y
                         + acc0[4 * is + 2] * xq0[is].z + acc0[4 * is + 3] * xq0[is].w;
                float r1 = acc1[4 * is] * xq1[is].x + acc1[4 * is + 1] * xq1[is].y
                         + acc1[4 * is + 2] * xq1[is].z + acc1[4 * is + 3] * xq1[is].w;
                r0 += __shfl_xor(r0, 32);           // sum the two p-halves
                r1 += __shfl_xor(r1, 32);
                float e = __expf(kh ? r1 : r0);     // lane(m,kh) owns b = kh*32+m
                float er;
                unsigned short eb = bf16_rne(e, er);
                e_t[(size_t)(i0 + is) * (N2_ * 64) + n * 64 + kh * 32 + m] = eb;
                dacc[is] += er;
            }
        }

        __syncthreads();    // dred may still be read by previous vb iteration
#pragma unroll
        for (int is = 0; is < 4; ++is) dred[wv][is][kh * 32 + m] = dacc[is];
        __syncthreads();
        {
            const int is2 = tid >> 6;
            const int b2  = tid & 63;
            float s = dred[0][is2][b2] + dred[1][is2][b2]
                    + dred[2][is2][b2] + dred[3][is2][b2];
            atomicAdd(&denom[(size_t)(i0 + is2) * 64 + b2], s);
        }
    }
    gbar(bar, 2);

    // ---------------- P4: s1 partials ----------------
    {
        const int col   = lane & 15;
        const int quad  = lane >> 4;
        const int n     = (blk & 31) * 4 + wv;
        const int isp   = blk >> 5;
        const int ibase = isp * CHUNK;

        f32x4 acc[4];
#pragma unroll
        for (int bt = 0; bt < 4; ++bt) acc[bt] = (f32x4){0.f, 0.f, 0.f, 0.f};

        for (int ib = 0; ib < NIB; ++ib) {
            const int iq = ibase + ib * 4 + quad;
            const float* wp = W + ((size_t)iq * N2_ + n) * (D_ * P_) + col * P_;
            float4 wa = *(const float4*)wp;
            float4 wb = *(const float4*)(wp + 4);
            bf16x8 ahi, alo;
            split_frag(wa, wb, ahi, alo);
#pragma unroll
            for (int bt = 0; bt < 4; ++bt) {
                const int b = bt * 16 + col;
                const float* xp = x + ((size_t)b * N1_ + iq) * P_;
                float4 xa = *(const float4*)xp;
                float4 xb = *(const float4*)(xp + 4);
                float e  = __uint_as_float((unsigned)e_t[((size_t)iq * N2_ + n) * 64 + b] << 16);
                float dv = denom[(size_t)iq * 64 + b];
                float c  = e * __builtin_amdgcn_rcpf(dv);
                float4 ya = make_float4(xa.x * c, xa.y * c, xa.z * c, xa.w * c);
                float4 yb = make_float4(xb.x * c, xb.y * c, xb.z * c, xb.w * c);
                bf16x8 bhi, blo;
                split_frag(ya, yb, bhi, blo);
                acc[bt] = __builtin_amdgcn_mfma_f32_16x16x32_bf16(ahi, bhi, acc[bt], 0, 0, 0);
                acc[bt] = __builtin_amdgcn_mfma_f32_16x16x32_bf16(ahi, blo, acc[bt], 0, 0, 0);
                acc[bt] = __builtin_amdgcn_mfma_f32_16x16x32_bf16(alo, bhi, acc[bt], 0, 0, 0);
            }
        }
#pragma unroll
        for (int bt = 0; bt < 4; ++bt) {
            const int b = bt * 16 + col;
            float4 v = make_float4(acc[bt][0], acc[bt][1], acc[bt][2], acc[bt][3]);
            *(float4*)(s_part + (size_t)isp * (B_ * N2_ * D_) + (size_t)b * (N2_ * D_)
                       + n * D_ + quad * 4) = v;
        }
    }
    gbar(bar, 3);

    // ---------------- P5: squash -> out ----------------
    if (blk < 128)
        squash_body(s_part, out, nullptr, nullptr, 1.f, blk * 256 + tid);
}

// ---------------------------------------------------------------------------
extern "C" void kernel_launch(void* const* d_in, const int* in_sizes, int n_in,
                              void* d_out, int out_size, void* d_ws, size_t ws_size,
                              hipStream_t stream)
{
    const float* x = (const float*)d_in[0];   // [64,1152,8]
    const float* W = (const float*)d_in[1];   // [1152,128,16,8]
    float* out = (float*)d_out;               // [64,128,16]

    float* s_part = (float*)d_ws;                               // 16*131072 floats (8.4 MB)
    float* v0     = s_part + (size_t)NSPLIT * B_ * N2_ * D_;    // 131072 floats
    float* denom  = v0 + B_ * N2_ * D_;                         // 73728 floats: [i][b]
    unsigned short* v0h = (unsigned short*)(denom + (size_t)N1_ * 64);   // 131072 bf16
    unsigned short* v0l = v0h + (size_t)B_ * N2_ * D_;                   // 131072 bf16
    unsigned short* e_t = v0l + (size_t)B_ * N2_ * D_;                   // 9437184 bf16
    unsigned* bar = (unsigned*)(e_t + (size_t)N1_ * N2_ * 64);           // 8 uints

    kinit <<<288,       256, 0, stream>>>(denom, bar);
    mega  <<<GRID_BLKS, 256, 0, stream>>>(x, W, out, s_part, v0, denom,
                                          v0h, v0l, e_t, bar);
}

// Round 9
// 435.167 us; speedup vs baseline: 1.5259x; 1.5259x over previous
//
#include <hip/hip_runtime.h>
#include <math.h>

// dims
#define B_   64
#define P_   8
#define N1_  1152
#define N2_  128
#define D_   16

#define NSPLIT 16                      // i-splits for P1/P4 partials
#define CHUNK  (N1_ / NSPLIT)          // 72 i per chunk
#define NIB    (CHUNK / 4)             // 18 i-blocks of 4

#define GRID_BLKS 512                  // == P1/P4 vblocks; 2 blocks/CU guaranteed resident

typedef __attribute__((ext_vector_type(8)))  short bf16x8;
typedef __attribute__((ext_vector_type(4)))  float f32x4;
typedef __attribute__((ext_vector_type(16))) float f32x16;

// split 8 fp32 into hi/lo bf16 fragments (hi = truncate, lo = bf16(w - hi))
__device__ inline void split_frag(float4 a0, float4 a1, bf16x8& hi, bf16x8& lo)
{
    float w[8] = {a0.x, a0.y, a0.z, a0.w, a1.x, a1.y, a1.z, a1.w};
#pragma unroll
    for (int j = 0; j < 8; ++j) {
        unsigned ub = __float_as_uint(w[j]);
        hi[j] = (short)(ub >> 16);
        float hif = __uint_as_float(ub & 0xffff0000u);
        float r = w[j] - hif;
        lo[j] = (short)(__float_as_uint(r) >> 16);
    }
}

__device__ inline void split_arr(const float* w, bf16x8& hi, bf16x8& lo)
{
#pragma unroll
    for (int j = 0; j < 8; ++j) {
        unsigned ub = __float_as_uint(w[j]);
        hi[j] = (short)(ub >> 16);
        float hif = __uint_as_float(ub & 0xffff0000u);
        float r = w[j] - hif;
        lo[j] = (short)(__float_as_uint(r) >> 16);
    }
}

// pack 4 fp32 into hi/lo bf16 uint2 (same split formula — bit-identical frags)
__device__ inline void split4_pack(float4 s, uint2& hp, uint2& lp)
{
    float w[4] = {s.x, s.y, s.z, s.w};
    unsigned hs[4], ls[4];
#pragma unroll
    for (int j = 0; j < 4; ++j) {
        unsigned ub = __float_as_uint(w[j]);
        hs[j] = ub >> 16;
        float hif = __uint_as_float(ub & 0xffff0000u);
        float r = w[j] - hif;
        ls[j] = __float_as_uint(r) >> 16;
    }
    hp.x = hs[0] | (hs[1] << 16); hp.y = hs[2] | (hs[3] << 16);
    lp.x = ls[0] | (ls[1] << 16); lp.y = ls[2] | (ls[3] << 16);
}

// round fp32 -> bf16 bits (RNE), and the dequantized fp32 value
__device__ inline unsigned short bf16_rne(float x, float& deq)
{
    unsigned ub = __float_as_uint(x);
    unsigned r  = ub + 0x7fffu + ((ub >> 16) & 1u);
    unsigned short us = (unsigned short)(r >> 16);
    deq = __uint_as_float(((unsigned)us) << 16);
    return us;
}

// Grid barrier, cache-friendly form. R8's version did an ACQUIRE agent load
// per spin iteration -> L2 invalidate per spin (per-XCD L2 non-coherent) ->
// every phase ran cold (593us, MfmaUtil 1.4%). Fix: RELAXED spin (reads the
// coherence point WITHOUT invalidating L2); exactly ONE release fence before
// arrival and ONE acquire fence after the condition — 2 cache ops per block
// per barrier, same as a kernel boundary.
__device__ inline void gbar(unsigned* __restrict__ bar, int k)
{
    __syncthreads();                          // all block lanes done with phase
    if (threadIdx.x == 0) {
        __threadfence();                      // release: write back our L2
        __hip_atomic_fetch_add(&bar[k], 1u, __ATOMIC_RELAXED, __HIP_MEMORY_SCOPE_AGENT);
        unsigned spins = 0;
        while (__hip_atomic_load(&bar[k], __ATOMIC_RELAXED, __HIP_MEMORY_SCOPE_AGENT)
               < (unsigned)GRID_BLKS) {
            __builtin_amdgcn_s_sleep(8);
            if (++spins > 100000000u) break;  // fail loud, not hung
        }
        __threadfence();                      // acquire: invalidate stale L1/L2 once
    }
    __syncthreads();
}

// squash phase body: reduce NSPLIT partials (float4), scale, squash over d=16.
__device__ inline void squash_body(const float* __restrict__ spart,
                                   float* __restrict__ vout,
                                   unsigned short* __restrict__ v0h,
                                   unsigned short* __restrict__ v0l,
                                   float scale, int idx)
{
    float4 s = make_float4(0.f, 0.f, 0.f, 0.f);
    for (int sp = 0; sp < NSPLIT; ++sp) {
        float4 t = *(const float4*)(spart + (size_t)sp * (B_ * N2_ * D_) + (size_t)idx * 4);
        s.x += t.x; s.y += t.y; s.z += t.z; s.w += t.w;
    }
    s.x *= scale; s.y *= scale; s.z *= scale; s.w *= scale;
    float sq = s.x * s.x + s.y * s.y + s.z * s.z + s.w * s.w;
    sq += __shfl_xor(sq, 1);
    sq += __shfl_xor(sq, 2);
    float norm = sqrtf(sq + 1.1920929e-7f);
    float f = (sq / (1.f + sq)) / norm;
    float4 o = make_float4(s.x * f, s.y * f, s.z * f, s.w * f);
    *(float4*)(vout + (size_t)idx * 4) = o;
    if (v0h) {
        uint2 hp, lp;
        split4_pack(o, hp, lp);
        *(uint2*)(v0h + (size_t)idx * 4) = hp;
        *(uint2*)(v0l + (size_t)idx * 4) = lp;
    }
}

// ---------------------------------------------------------------------------
// MEGA: all 5 phases, one plain dispatch, hand-rolled grid barriers.
//  P1: s0 partials (512 vblocks == 512 blocks; R5 k1 body, direct-x split)
//  P2: squash->v0 (+bf16 planes) [blk<128]; zero denom [blk>=128]
//  P3: e_t=bf16(exp(<v0,pred>)) + denom atomics (1152 vblocks, stride 512)
//  P4: s1 partials (512 vblocks; R5 k3c body)
//  P5: squash->out               [blk<128]
// ---------------------------------------------------------------------------
__global__ __launch_bounds__(256, 2) void mega(const float* __restrict__ x,
                                               const float* __restrict__ W,
                                               float* __restrict__ out,
                                               float* __restrict__ s_part,
                                               float* __restrict__ v0,
                                               float* __restrict__ denom,
                                               unsigned short* __restrict__ v0h,
                                               unsigned short* __restrict__ v0l,
                                               unsigned short* __restrict__ e_t,
                                               unsigned* __restrict__ bar)
{
    const int blk  = blockIdx.x;
    const int tid  = threadIdx.x;
    const int lane = tid & 63;
    const int wv   = tid >> 6;

    __shared__ float dred[4][4][64];

    // ---------------- P1: s0 partials ----------------
    {
        const int col   = lane & 15;
        const int quad  = lane >> 4;
        const int n     = (blk & 31) * 4 + wv;
        const int isp   = blk >> 5;
        const int ibase = isp * CHUNK;

        f32x4 acc[4];
#pragma unroll
        for (int bt = 0; bt < 4; ++bt) acc[bt] = (f32x4){0.f, 0.f, 0.f, 0.f};

        for (int ib = 0; ib < NIB; ++ib) {
            const int iq = ibase + ib * 4 + quad;
            const float* wp = W + ((size_t)iq * N2_ + n) * (D_ * P_) + col * P_;
            float4 wa = *(const float4*)wp;
            float4 wb = *(const float4*)(wp + 4);
            bf16x8 ahi, alo;
            split_frag(wa, wb, ahi, alo);
#pragma unroll
            for (int bt = 0; bt < 4; ++bt) {
                const int b = bt * 16 + col;
                const float* xp = x + ((size_t)b * N1_ + iq) * P_;
                float4 xa = *(const float4*)xp;
                float4 xb = *(const float4*)(xp + 4);
                bf16x8 bhi, blo;
                split_frag(xa, xb, bhi, blo);
                acc[bt] = __builtin_amdgcn_mfma_f32_16x16x32_bf16(ahi, bhi, acc[bt], 0, 0, 0);
                acc[bt] = __builtin_amdgcn_mfma_f32_16x16x32_bf16(ahi, blo, acc[bt], 0, 0, 0);
                acc[bt] = __builtin_amdgcn_mfma_f32_16x16x32_bf16(alo, bhi, acc[bt], 0, 0, 0);
            }
        }
#pragma unroll
        for (int bt = 0; bt < 4; ++bt) {
            const int b = bt * 16 + col;
            float4 v = make_float4(acc[bt][0], acc[bt][1], acc[bt][2], acc[bt][3]);
            *(float4*)(s_part + (size_t)isp * (B_ * N2_ * D_) + (size_t)b * (N2_ * D_)
                       + n * D_ + quad * 4) = v;
        }
    }
    gbar(bar, 0);

    // ---------------- P2: squash -> v0 (+planes) / zero denom ----------------
    if (blk < 128) {
        squash_body(s_part, v0, v0h, v0l, 1.f / 128.f, blk * 256 + tid);
    } else {
        int z = (blk - 128) * 256 + tid;
        if (z < N1_ * 64) denom[z] = 0.f;
    }
    gbar(bar, 1);

    // ---------------- P3: e_t + denom (1152 vblocks, stride 512) ----------
    for (int vb = blk; vb < 1152; vb += GRID_BLKS) {
        const int m    = lane & 31;
        const int kh   = lane >> 5;         // d-half in MFMA / p-half in epilogue
        const int isub = m >> 3;
        const int p    = m & 7;
        const int i0   = (vb >> 2) * 4;
        const int nbase = (vb & 3) * 32 + wv * 8;

        float4 xq0[4], xq1[4];
#pragma unroll
        for (int is = 0; is < 4; ++is) {
            xq0[is] = *(const float4*)(x + ((size_t)m * N1_ + i0 + is) * P_ + kh * 4);
            xq1[is] = *(const float4*)(x + ((size_t)(32 + m) * N1_ + i0 + is) * P_ + kh * 4);
        }

        float dacc[4] = {0.f, 0.f, 0.f, 0.f};

#pragma unroll 1
        for (int nt = 0; nt < 8; ++nt) {
            const int n = nbase + nt;

            bf16x8 vhi[2], vlo[2];
#pragma unroll
            for (int bt = 0; bt < 2; ++bt) {
                const size_t vo = (size_t)(bt * 32 + m) * (N2_ * D_) + n * D_ + kh * 8;
                vhi[bt] = *(const bf16x8*)(v0h + vo);
                vlo[bt] = *(const bf16x8*)(v0l + vo);
            }

            const float* wp = W + ((size_t)(i0 + isub) * N2_ + n) * (D_ * P_) + kh * 64 + p;
            float a[8];
#pragma unroll
            for (int j = 0; j < 8; ++j) a[j] = wp[8 * j];
            bf16x8 ahi, alo;
            split_arr(a, ahi, alo);

            f32x16 acc0, acc1;
#pragma unroll
            for (int r = 0; r < 16; ++r) { acc0[r] = 0.f; acc1[r] = 0.f; }
            acc0 = __builtin_amdgcn_mfma_f32_32x32x16_bf16(ahi, vhi[0], acc0, 0, 0, 0);
            acc0 = __builtin_amdgcn_mfma_f32_32x32x16_bf16(ahi, vlo[0], acc0, 0, 0, 0);
            acc0 = __builtin_amdgcn_mfma_f32_32x32x16_bf16(alo, vhi[0], acc0, 0, 0, 0);
            acc1 = __builtin_amdgcn_mfma_f32_32x32x16_bf16(ahi, vhi[1], acc1, 0, 0, 0);
            acc1 = __builtin_amdgcn_mfma_f32_32x32x16_bf16(ahi, vlo[1], acc1, 0, 0, 0);
            acc1 = __builtin_amdgcn_mfma_f32_32x32x16_bf16(alo, vhi[1], acc1, 0, 0, 0);

#pragma unroll
            for (int is = 0; is < 4; ++is) {
                float r0 = acc0[4 * is] * xq0[is].x + acc0[4 * is + 1] * xq0[is].y
                         + acc0[4 * is + 2] * xq0[is].z + acc0[4 * is + 3] * xq0[is].w;
                float r1 = acc1[4 * is] * xq1[is].x + acc1[4 * is + 1] * xq1[is].y
                         + acc1[4 * is + 2] * xq1[is].z + acc1[4 * is + 3] * xq1[is].w;
                r0 += __shfl_xor(r0, 32);           // sum the two p-halves
                r1 += __shfl_xor(r1, 32);
                float e = __expf(kh ? r1 : r0);     // lane(m,kh) owns b = kh*32+m
                float er;
                unsigned short eb = bf16_rne(e, er);
                e_t[(size_t)(i0 + is) * (N2_ * 64) + n * 64 + kh * 32 + m] = eb;
                dacc[is] += er;
            }
        }

        __syncthreads();    // dred may still be read by previous vb iteration
#pragma unroll
        for (int is = 0; is < 4; ++is) dred[wv][is][kh * 32 + m] = dacc[is];
        __syncthreads();
        {
            const int is2 = tid >> 6;
            const int b2  = tid & 63;
            float s = dred[0][is2][b2] + dred[1][is2][b2]
                    + dred[2][is2][b2] + dred[3][is2][b2];
            atomicAdd(&denom[(size_t)(i0 + is2) * 64 + b2], s);
        }
    }
    gbar(bar, 2);

    // ---------------- P4: s1 partials ----------------
    {
        const int col   = lane & 15;
        const int quad  = lane >> 4;
        const int n     = (blk & 31) * 4 + wv;
        const int isp   = blk >> 5;
        const int ibase = isp * CHUNK;

        f32x4 acc[4];
#pragma unroll
        for (int bt = 0; bt < 4; ++bt) acc[bt] = (f32x4){0.f, 0.f, 0.f, 0.f};

        for (int ib = 0; ib < NIB; ++ib) {
            const int iq = ibase + ib * 4 + quad;
            const float* wp = W + ((size_t)iq * N2_ + n) * (D_ * P_) + col * P_;
            float4 wa = *(const float4*)wp;
            float4 wb = *(const float4*)(wp + 4);
            bf16x8 ahi, alo;
            split_frag(wa, wb, ahi, alo);
#pragma unroll
            for (int bt = 0; bt < 4; ++bt) {
                const int b = bt * 16 + col;
                const float* xp = x + ((size_t)b * N1_ + iq) * P_;
                float4 xa = *(const float4*)xp;
                float4 xb = *(const float4*)(xp + 4);
                float e  = __uint_as_float((unsigned)e_t[((size_t)iq * N2_ + n) * 64 + b] << 16);
                float dv = denom[(size_t)iq * 64 + b];
                float c  = e * __builtin_amdgcn_rcpf(dv);
                float4 ya = make_float4(xa.x * c, xa.y * c, xa.z * c, xa.w * c);
                float4 yb = make_float4(xb.x * c, xb.y * c, xb.z * c, xb.w * c);
                bf16x8 bhi, blo;
                split_frag(ya, yb, bhi, blo);
                acc[bt] = __builtin_amdgcn_mfma_f32_16x16x32_bf16(ahi, bhi, acc[bt], 0, 0, 0);
                acc[bt] = __builtin_amdgcn_mfma_f32_16x16x32_bf16(ahi, blo, acc[bt], 0, 0, 0);
                acc[bt] = __builtin_amdgcn_mfma_f32_16x16x32_bf16(alo, bhi, acc[bt], 0, 0, 0);
            }
        }
#pragma unroll
        for (int bt = 0; bt < 4; ++bt) {
            const int b = bt * 16 + col;
            float4 v = make_float4(acc[bt][0], acc[bt][1], acc[bt][2], acc[bt][3]);
            *(float4*)(s_part + (size_t)isp * (B_ * N2_ * D_) + (size_t)b * (N2_ * D_)
                       + n * D_ + quad * 4) = v;
        }
    }
    gbar(bar, 3);

    // ---------------- P5: squash -> out ----------------
    if (blk < 128)
        squash_body(s_part, out, nullptr, nullptr, 1.f, blk * 256 + tid);
}

// ---------------------------------------------------------------------------
extern "C" void kernel_launch(void* const* d_in, const int* in_sizes, int n_in,
                              void* d_out, int out_size, void* d_ws, size_t ws_size,
                              hipStream_t stream)
{
    const float* x = (const float*)d_in[0];   // [64,1152,8]
    const float* W = (const float*)d_in[1];   // [1152,128,16,8]
    float* out = (float*)d_out;               // [64,128,16]

    float* s_part = (float*)d_ws;                               // 16*131072 floats (8.4 MB)
    float* v0     = s_part + (size_t)NSPLIT * B_ * N2_ * D_;    // 131072 floats
    float* denom  = v0 + B_ * N2_ * D_;                         // 73728 floats: [i][b]
    unsigned short* v0h = (unsigned short*)(denom + (size_t)N1_ * 64);   // 131072 bf16
    unsigned short* v0l = v0h + (size_t)B_ * N2_ * D_;                   // 131072 bf16
    unsigned short* e_t = v0l + (size_t)B_ * N2_ * D_;                   // 9437184 bf16
    unsigned* bar = (unsigned*)(e_t + (size_t)N1_ * N2_ * 64);           // 8 uints

    hipMemsetAsync(bar, 0, 8 * sizeof(unsigned), stream);
    mega <<<GRID_BLKS, 256, 0, stream>>>(x, W, out, s_part, v0, denom,
                                         v0h, v0l, e_t, bar);
}